// Round 1
// baseline (65.323 us; speedup 1.0000x reference)
//
#include <hip/hip_runtime.h>
#include <math.h>

#define G 128
#define C 50
#define HEADS 3

// ws float layout
#define WS_M1   0        // [2][768]
#define WS_M2   1536     // [2][768]
#define WS_CV   3072     // [768]
#define WS_SC   3840     // 30 scalars: src [h*5+r] (15), then dst (15)
#define WS_P    3872     // [15][128]  Bas @ w1[256:512]
#define WS_Q    5792     // [15][128]  Bas @ w1[0:256]
#define WS_HC   7712     // [128]      gat_b@(w1_top+w1_bot) + b1
#define WS_TOTAL 7840

// ---------------- K0a: M1, M2, cvec ----------------
__global__ __launch_bounds__(256) void k0a(const float* __restrict__ w0,
                                           const float* __restrict__ b0,
                                           const float* __restrict__ gw,
                                           float* __restrict__ ws) {
  int u = blockIdx.x * 256 + threadIdx.x;
  if (u < 1536) {
    int f = u / 768, c = u % 768;
    float acc = 0.f;
    for (int k = 0; k < 128; ++k) acc += w0[f * 128 + k] * gw[k * 768 + c];
    ws[WS_M1 + u] = acc;
  } else if (u < 3072) {
    int v = u - 1536;
    int f = v / 768, c = v % 768;
    float acc = 0.f;
    for (int k = 0; k < 128; ++k) acc += w0[f * 128 + k] * gw[(128 + k) * 768 + c];
    ws[WS_M2 + v] = acc;
  } else if (u < 3840) {
    int c = u - 3072;
    float acc = 0.f;
    for (int k = 0; k < 128; ++k)
      acc += b0[k] * (gw[k * 768 + c] + gw[(128 + k) * 768 + c]);
    ws[WS_CV + c] = acc;
  }
}

__device__ __forceinline__ float bas_val(const float* __restrict__ ws, int h, int r, int k) {
  int col = h * 256 + k;
  if (r == 0) return ws[WS_M1 + col];
  if (r == 1) return ws[WS_M1 + 768 + col];
  if (r == 2) return ws[WS_M2 + col];
  if (r == 3) return ws[WS_M2 + 768 + col];
  return ws[WS_CV + col];
}

// ---------------- K0b: P, Q, attention scalars, hc ----------------
__global__ __launch_bounds__(256) void k0b(const float* __restrict__ att_src,
                                           const float* __restrict__ att_dst,
                                           const float* __restrict__ w1,
                                           const float* __restrict__ b1,
                                           const float* __restrict__ gat_b,
                                           float* __restrict__ ws) {
  int u = blockIdx.x * 256 + threadIdx.x;
  if (u < 1920) {
    int t = u / 128, c = u % 128;
    int h = t / 5, r = t % 5;
    float acc = 0.f;
    for (int k = 0; k < 256; ++k) acc += bas_val(ws, h, r, k) * w1[(256 + k) * 128 + c];
    ws[WS_P + u] = acc;
  } else if (u < 3840) {
    int v = u - 1920;
    int t = v / 128, c = v % 128;
    int h = t / 5, r = t % 5;
    float acc = 0.f;
    for (int k = 0; k < 256; ++k) acc += bas_val(ws, h, r, k) * w1[k * 128 + c];
    ws[WS_Q + v] = acc;
  } else if (u < 3870) {
    int v = u - 3840;                 // 0..29
    int isdst = v / 15, t = v % 15;
    int h = t / 5, r = t % 5;
    const float* att = isdst ? att_dst : att_src;
    float acc = 0.f;
    for (int k = 0; k < 256; ++k) acc += bas_val(ws, h, r, k) * att[h * 256 + k];
    ws[WS_SC + v] = acc;
  } else if (u < 3998) {
    int c = u - 3870;
    float acc = b1[c];
    for (int k = 0; k < 256; ++k)
      acc += gat_b[k] * (w1[k * 128 + c] + w1[(256 + k) * 128 + c]);
    ws[WS_HC + c] = acc;
  }
}

// ---------------- K1: one block per graph ----------------
__global__ __launch_bounds__(256) void k1(const float* __restrict__ x,
                                          const int* __restrict__ prev,
                                          const int* __restrict__ cni,
                                          const int* __restrict__ gid,
                                          const float* __restrict__ w2,
                                          const float* __restrict__ b2,
                                          const float* __restrict__ ws,
                                          float* __restrict__ out) {
  __shared__ float s_x[C][2], s_xp[C][2];
  __shared__ float s_as[HEADS][C], s_ad[HEADS][C];
  __shared__ float s_co[C][17];
  __shared__ float s_h1[C][129];
  __shared__ float s_logits[64];
  __shared__ float s_w2[132];

  int g = blockIdx.x;
  int t = threadIdx.x;
  int base = g * C;

  if (t < C) {
    int p = prev[base + t];
    s_x[t][0] = x[(base + t) * 2 + 0];
    s_x[t][1] = x[(base + t) * 2 + 1];
    s_xp[t][0] = x[p * 2 + 0];
    s_xp[t][1] = x[p * 2 + 1];
  }
  if (t < 130) s_w2[t] = w2[t];
  __syncthreads();

  // attention pre-activations: 5-term dots per (head, node)
  if (t < HEADS * C) {
    int h = t / C, j = t % C;
    float xp0 = s_xp[j][0], xp1 = s_xp[j][1], x0 = s_x[j][0], x1 = s_x[j][1];
    const float* sc = ws + WS_SC + h * 5;
    const float* dc = ws + WS_SC + 15 + h * 5;
    s_as[h][j] = xp0 * sc[0] + xp1 * sc[1] + x0 * sc[2] + x1 * sc[3] + sc[4];
    s_ad[h][j] = xp0 * dc[0] + xp1 * dc[1] + x0 * dc[2] + x1 * dc[3] + dc[4];
  }
  __syncthreads();

  // per (head, dst j): softmax over src i, rank-5 coefficients
  if (t < HEADS * C) {
    int h = t / C, j = t % C;
    float adj = s_ad[h][j];
    float m = -1e30f;
    for (int i = 0; i < C; ++i) {
      float e = s_as[h][i] + adj;
      e = fmaxf(e, 0.2f * e);           // leaky_relu(0.2)
      m = fmaxf(m, e);
    }
    float sum = 0.f, c0 = 0.f, c1 = 0.f, c2 = 0.f, c3 = 0.f;
    for (int i = 0; i < C; ++i) {
      float e = s_as[h][i] + adj;
      e = fmaxf(e, 0.2f * e);
      float ex = __expf(e - m);
      sum += ex;
      c0 += ex * s_xp[i][0];
      c1 += ex * s_xp[i][1];
      c2 += ex * s_x[i][0];
      c3 += ex * s_x[i][1];
    }
    float inv = 1.0f / (3.0f * sum);    // fold head-mean and softmax denom
    s_co[j][h * 5 + 0] = c0 * inv;
    s_co[j][h * 5 + 1] = c1 * inv;
    s_co[j][h * 5 + 2] = c2 * inv;
    s_co[j][h * 5 + 3] = c3 * inv;
    s_co[j][h * 5 + 4] = sum * inv;
  }
  __syncthreads();

  // h1[j][c] = relu(hc[c] + sum_r co[center][r]*Q[r][c] + co[j][r]*P[r][c])
  {
    int c0l = cni[g] - base;
    int c = t & 127;
    int jh = t >> 7;                    // 0 or 1
    const float* P = ws + WS_P;
    const float* Q = ws + WS_Q;
    float cen = ws[WS_HC + c];
    for (int r = 0; r < 15; ++r) cen += s_co[c0l][r] * Q[r * 128 + c];
    for (int mm = 0; mm < 25; ++mm) {
      int j = jh + 2 * mm;
      float acc = cen;
      for (int r = 0; r < 15; ++r) acc += s_co[j][r] * P[r * 128 + c];
      s_h1[j][c] = fmaxf(acc, 0.f);
    }
  }
  __syncthreads();

  // logits[j] = b2 + x.w2[0:2] + h1.w2[2:130]
  if (t < C) {
    float acc = b2[0] + s_x[t][0] * s_w2[0] + s_x[t][1] * s_w2[1];
    for (int k = 0; k < 128; ++k) acc += s_h1[t][k] * s_w2[2 + k];
    s_logits[t] = acc;
  }
  __syncthreads();

  // wave-0 softmax + argmax over 50 cities
  if (t < 64) {
    float v = (t < C) ? s_logits[t] : -1e30f;
    float mv = v; int mi = t;
    for (int off = 32; off > 0; off >>= 1) {
      float ov = __shfl_xor(mv, off);
      int oi = __shfl_xor(mi, off);
      if (ov > mv || (ov == mv && oi < mi)) { mv = ov; mi = oi; }
    }
    float ex = (t < C) ? __expf(v - mv) : 0.f;
    for (int off = 32; off > 0; off >>= 1) ex += __shfl_xor(ex, off);
    if (t == 0) {
      out[g] = (float)(mi + gid[g]);      // sample + graph_id_index
      out[G + g] = -logf(ex);             // log prob of argmax
    }
  }
}

extern "C" void kernel_launch(void* const* d_in, const int* in_sizes, int n_in,
                              void* d_out, int out_size, void* d_ws, size_t ws_size,
                              hipStream_t stream) {
  const float* x    = (const float*)d_in[0];
  const int*   prev = (const int*)d_in[2];
  const int*   cni  = (const int*)d_in[3];
  const int*   gid  = (const int*)d_in[4];
  const float* w0   = (const float*)d_in[6];
  const float* b0   = (const float*)d_in[7];
  const float* gw   = (const float*)d_in[8];
  const float* asrc = (const float*)d_in[9];
  const float* adst = (const float*)d_in[10];
  const float* gb   = (const float*)d_in[11];
  const float* w1   = (const float*)d_in[12];
  const float* b1   = (const float*)d_in[13];
  const float* w2   = (const float*)d_in[14];
  const float* b2   = (const float*)d_in[15];
  float* ws  = (float*)d_ws;
  float* out = (float*)d_out;

  k0a<<<15, 256, 0, stream>>>(w0, b0, gw, ws);
  k0b<<<16, 256, 0, stream>>>(asrc, adst, w1, b1, gb, ws);
  k1<<<G, 256, 0, stream>>>(x, prev, cni, gid, w2, b2, ws, out);
}

// Round 2
// 22.677 us; speedup vs baseline: 2.8806x; 2.8806x over previous
//
#include <hip/hip_runtime.h>
#include <math.h>

#define G 128
#define C 50
#define HEADS 3

// ws float layout (M1/M2/CV contiguous: 0..3839)
#define WS_M1   0        // [2][768]
#define WS_M2   1536     // [2][768]
#define WS_CV   3072     // [768]
#define WS_SC   3840     // 30 scalars: src [h*5+r] (15), then dst (15)
#define WS_P    3872     // [15][128]  Bas @ w1[256:512]
#define WS_Q    5792     // [15][128]  Bas @ w1[0:256]
#define WS_HC   7712     // [128]      gat_b@(w1_top+w1_bot) + b1
#define WS_TOTAL 7840

__device__ __forceinline__ int bas_off(int h, int r) {
  return (r < 2 ? r * 768 : (r < 4 ? 1536 + (r - 2) * 768 : 3072)) + h * 256;
}

// ---------------- K0a: M1, M2, CV ----------------
// 60 blocks; each block: 64 consecutive outputs x 4 k-chunks (32 each).
__global__ __launch_bounds__(256) void k0a(const float* __restrict__ w0,
                                           const float* __restrict__ b0,
                                           const float* __restrict__ gw,
                                           float* __restrict__ ws) {
  __shared__ float red[4][64];
  int u0 = blockIdx.x * 64;
  int q  = threadIdx.x >> 6;
  int ol = threadIdx.x & 63;
  int u  = u0 + ol;
  int k0 = q * 32;
  float acc = 0.f;
  if (u < 1536) {
    int f = u / 768, c = u % 768;
    const float* wr = w0 + f * 128 + k0;
    const float* gp = gw + k0 * 768 + c;
    #pragma unroll
    for (int i = 0; i < 32; ++i) acc += wr[i] * gp[i * 768];
  } else if (u < 3072) {
    int v = u - 1536;
    int f = v / 768, c = v % 768;
    const float* wr = w0 + f * 128 + k0;
    const float* gp = gw + (128 + k0) * 768 + c;
    #pragma unroll
    for (int i = 0; i < 32; ++i) acc += wr[i] * gp[i * 768];
  } else {
    int c = u - 3072;
    const float* br = b0 + k0;
    const float* g1 = gw + k0 * 768 + c;
    const float* g2 = gw + (128 + k0) * 768 + c;
    #pragma unroll
    for (int i = 0; i < 32; ++i) acc += br[i] * (g1[i * 768] + g2[i * 768]);
  }
  red[q][ol] = acc;
  __syncthreads();
  if (threadIdx.x < 64) {
    ws[u0 + threadIdx.x] = red[0][threadIdx.x] + red[1][threadIdx.x] +
                           red[2][threadIdx.x] + red[3][threadIdx.x];
  }
}

// ---------------- K0b: P, Q, SC, HC ----------------
// blocks 0..29: P (64 outputs each), 30..59: Q, 60: SC, 61: HC
__global__ __launch_bounds__(256) void k0b(const float* __restrict__ att_src,
                                           const float* __restrict__ att_dst,
                                           const float* __restrict__ w1,
                                           const float* __restrict__ b1,
                                           const float* __restrict__ gat_b,
                                           float* __restrict__ ws) {
  __shared__ float red[4][64];
  __shared__ float hred[2][128];
  int blk = blockIdx.x;
  int tid = threadIdx.x;

  if (blk < 60) {
    int isP = blk < 30;
    int u0 = (isP ? blk : blk - 30) * 64;
    int q  = tid >> 6;
    int ol = tid & 63;
    int u  = u0 + ol;
    int t  = u / 128, c = u % 128;
    int h = t / 5, r = t % 5;
    const float* bas = ws + bas_off(h, r);
    const float* w1p = w1 + ((isP ? 256 : 0) + q * 64) * 128 + c;
    int k0 = q * 64;
    float acc = 0.f;
    #pragma unroll
    for (int i = 0; i < 64; ++i) acc += bas[k0 + i] * w1p[i * 128];
    red[q][ol] = acc;
    __syncthreads();
    if (tid < 64) {
      float s = red[0][tid] + red[1][tid] + red[2][tid] + red[3][tid];
      ws[(isP ? WS_P : WS_Q) + u0 + tid] = s;
    }
  } else if (blk == 60) {
    // 30 outputs, 8 lanes each (groups of 8 within a wave)
    int v = tid >> 3, kk = tid & 7;
    float acc = 0.f;
    if (v < 30) {
      int isdst = v / 15, tt = v % 15;
      int h = tt / 5, r = tt % 5;
      const float* att = (isdst ? att_dst : att_src) + h * 256 + kk * 32;
      const float* bas = ws + bas_off(h, r) + kk * 32;
      #pragma unroll
      for (int i = 0; i < 32; ++i) acc += bas[i] * att[i];
    }
    acc += __shfl_xor(acc, 1);
    acc += __shfl_xor(acc, 2);
    acc += __shfl_xor(acc, 4);
    if (v < 30 && kk == 0) ws[WS_SC + v] = acc;
  } else {
    // HC: 128 outputs, 2 halves of k
    int c = tid & 127, half = tid >> 7;
    const float* w1a = w1 + (half * 128) * 128 + c;
    const float* w1b = w1 + (256 + half * 128) * 128 + c;
    const float* gbp = gat_b + half * 128;
    float acc = 0.f;
    #pragma unroll 32
    for (int i = 0; i < 128; ++i) acc += gbp[i] * (w1a[i * 128] + w1b[i * 128]);
    hred[half][c] = acc;
    __syncthreads();
    if (tid < 128) ws[WS_HC + tid] = b1[tid] + hred[0][tid] + hred[1][tid];
  }
}

// ---------------- K1: one block per graph ----------------
__global__ __launch_bounds__(256) void k1(const float* __restrict__ x,
                                          const int* __restrict__ prev,
                                          const int* __restrict__ cni,
                                          const int* __restrict__ gid,
                                          const float* __restrict__ w2,
                                          const float* __restrict__ b2,
                                          const float* __restrict__ ws,
                                          float* __restrict__ out) {
  __shared__ float s_x[C][2], s_xp[C][2];
  __shared__ float s_as[HEADS][C], s_ad[HEADS][C];
  __shared__ float s_co[C][17];
  __shared__ float s_h1[C][129];
  __shared__ float s_logits[64];
  __shared__ float s_w2[132];

  int g = blockIdx.x;
  int t = threadIdx.x;
  int base = g * C;

  if (t < C) {
    int p = prev[base + t];
    s_x[t][0] = x[(base + t) * 2 + 0];
    s_x[t][1] = x[(base + t) * 2 + 1];
    s_xp[t][0] = x[p * 2 + 0];
    s_xp[t][1] = x[p * 2 + 1];
  }
  if (t < 130) s_w2[t] = w2[t];
  __syncthreads();

  if (t < HEADS * C) {
    int h = t / C, j = t % C;
    float xp0 = s_xp[j][0], xp1 = s_xp[j][1], x0 = s_x[j][0], x1 = s_x[j][1];
    const float* sc = ws + WS_SC + h * 5;
    const float* dc = ws + WS_SC + 15 + h * 5;
    s_as[h][j] = xp0 * sc[0] + xp1 * sc[1] + x0 * sc[2] + x1 * sc[3] + sc[4];
    s_ad[h][j] = xp0 * dc[0] + xp1 * dc[1] + x0 * dc[2] + x1 * dc[3] + dc[4];
  }
  __syncthreads();

  if (t < HEADS * C) {
    int h = t / C, j = t % C;
    float adj = s_ad[h][j];
    float m = -1e30f;
    for (int i = 0; i < C; ++i) {
      float e = s_as[h][i] + adj;
      e = fmaxf(e, 0.2f * e);
      m = fmaxf(m, e);
    }
    float sum = 0.f, c0 = 0.f, c1 = 0.f, c2 = 0.f, c3 = 0.f;
    for (int i = 0; i < C; ++i) {
      float e = s_as[h][i] + adj;
      e = fmaxf(e, 0.2f * e);
      float ex = __expf(e - m);
      sum += ex;
      c0 += ex * s_xp[i][0];
      c1 += ex * s_xp[i][1];
      c2 += ex * s_x[i][0];
      c3 += ex * s_x[i][1];
    }
    float inv = 1.0f / (3.0f * sum);
    s_co[j][h * 5 + 0] = c0 * inv;
    s_co[j][h * 5 + 1] = c1 * inv;
    s_co[j][h * 5 + 2] = c2 * inv;
    s_co[j][h * 5 + 3] = c3 * inv;
    s_co[j][h * 5 + 4] = sum * inv;
  }
  __syncthreads();

  // h1[j][c] = relu(hc[c] + co[center].Qcol + co[j].Pcol)
  {
    int c0l = cni[g] - base;
    int c = t & 127;
    int jh = t >> 7;
    float Pcol[15], Qcol[15];
    #pragma unroll
    for (int r = 0; r < 15; ++r) {
      Pcol[r] = ws[WS_P + r * 128 + c];
      Qcol[r] = ws[WS_Q + r * 128 + c];
    }
    float cen = ws[WS_HC + c];
    #pragma unroll
    for (int r = 0; r < 15; ++r) cen += s_co[c0l][r] * Qcol[r];
    for (int mm = 0; mm < 25; ++mm) {
      int j = jh + 2 * mm;
      float acc = cen;
      #pragma unroll
      for (int r = 0; r < 15; ++r) acc += s_co[j][r] * Pcol[r];
      s_h1[j][c] = fmaxf(acc, 0.f);
    }
  }
  __syncthreads();

  // logits: 4 lanes per city
  if (t < 200) {
    int j = t >> 2, kk = t & 3;
    float acc = 0.f;
    #pragma unroll
    for (int k = 0; k < 32; ++k) acc += s_h1[j][kk * 32 + k] * s_w2[2 + kk * 32 + k];
    acc += __shfl_xor(acc, 1);
    acc += __shfl_xor(acc, 2);
    if (kk == 0)
      s_logits[j] = acc + b2[0] + s_x[j][0] * s_w2[0] + s_x[j][1] * s_w2[1];
  }
  __syncthreads();

  if (t < 64) {
    float v = (t < C) ? s_logits[t] : -1e30f;
    float mv = v; int mi = t;
    for (int off = 32; off > 0; off >>= 1) {
      float ov = __shfl_xor(mv, off);
      int oi = __shfl_xor(mi, off);
      if (ov > mv || (ov == mv && oi < mi)) { mv = ov; mi = oi; }
    }
    float ex = (t < C) ? __expf(v - mv) : 0.f;
    for (int off = 32; off > 0; off >>= 1) ex += __shfl_xor(ex, off);
    if (t == 0) {
      out[g] = (float)(mi + gid[g]);
      out[G + g] = -logf(ex);
    }
  }
}

extern "C" void kernel_launch(void* const* d_in, const int* in_sizes, int n_in,
                              void* d_out, int out_size, void* d_ws, size_t ws_size,
                              hipStream_t stream) {
  const float* x    = (const float*)d_in[0];
  const int*   prev = (const int*)d_in[2];
  const int*   cni  = (const int*)d_in[3];
  const int*   gid  = (const int*)d_in[4];
  const float* w0   = (const float*)d_in[6];
  const float* b0   = (const float*)d_in[7];
  const float* gw   = (const float*)d_in[8];
  const float* asrc = (const float*)d_in[9];
  const float* adst = (const float*)d_in[10];
  const float* gb   = (const float*)d_in[11];
  const float* w1   = (const float*)d_in[12];
  const float* b1   = (const float*)d_in[13];
  const float* w2   = (const float*)d_in[14];
  const float* b2   = (const float*)d_in[15];
  float* ws  = (float*)d_ws;
  float* out = (float*)d_out;

  k0a<<<60, 256, 0, stream>>>(w0, b0, gw, ws);
  k0b<<<62, 256, 0, stream>>>(asrc, adst, w1, b1, gb, ws);
  k1<<<G, 256, 0, stream>>>(x, prev, cni, gid, w2, b2, ws, out);
}

// Round 3
// 21.389 us; speedup vs baseline: 3.0541x; 1.0602x over previous
//
#include <hip/hip_runtime.h>
#include <math.h>

#define G 128
#define C 50
#define HEADS 3

// ws float layout
#define WS_SC   0        // 30 scalars: src [h*5+r] (15), then dst (15)
#define WS_P    32       // [15][128]  Bas @ w1[256:512]
#define WS_Q    1952     // [15][128]  Bas @ w1[0:256]
#define WS_HC   3872     // [128]      gat_b@(w1_top+w1_bot) + b1
#define WS_TOTAL 4000

// ---------------- kpre: P, Q, SC, HC in one kernel, 31 independent blocks ----
// blocks 0..14 : P row t (h=t/5, r=t%5) + SC src/dst scalars for (h,r)
// blocks 15..29: Q row t-15
// block  30    : HC
__global__ __launch_bounds__(256) void kpre(const float* __restrict__ w0,
                                            const float* __restrict__ b0,
                                            const float* __restrict__ gw,
                                            const float* __restrict__ asrc,
                                            const float* __restrict__ adst,
                                            const float* __restrict__ w1,
                                            const float* __restrict__ b1,
                                            const float* __restrict__ gb,
                                            float* __restrict__ ws) {
  int blk = blockIdx.x;
  int tid = threadIdx.x;

  if (blk < 30) {
    __shared__ float s_bas[256];
    __shared__ float s_red[256];
    int isP = blk < 15;
    int t = isP ? blk : blk - 15;
    int h = t / 5, r = t % 5;

    // --- recompute Bas row (h,r): one k-element per thread, coalesced gw reads
    {
      int col = h * 256 + tid;
      float acc = 0.f;
      if (r < 4) {
        const float* wr = w0 + (r & 1) * 128;              // w0 row (broadcast)
        const float* gp = gw + (r < 2 ? 0 : 128 * 768) + col;
        #pragma unroll 32
        for (int m = 0; m < 128; ++m) acc += wr[m] * gp[m * 768];
      } else {
        const float* gp = gw + col;
        #pragma unroll 32
        for (int m = 0; m < 128; ++m)
          acc += b0[m] * (gp[m * 768] + gp[(128 + m) * 768]);
      }
      s_bas[tid] = acc;
    }
    __syncthreads();

    // --- P/Q row: 128 outputs, k split in 2 halves across tid/tid+128
    {
      int c = tid & 127, half = tid >> 7;
      const float* w1p = w1 + ((isP ? 256 : 0) + half * 128) * 128 + c;
      const float* bp = s_bas + half * 128;
      float acc = 0.f;
      #pragma unroll 32
      for (int i = 0; i < 128; ++i) acc += bp[i] * w1p[i * 128];
      s_red[tid] = acc;
    }
    __syncthreads();
    if (tid < 128)
      ws[(isP ? WS_P : WS_Q) + t * 128 + tid] = s_red[tid] + s_red[tid + 128];

    // --- SC scalars (P blocks only): dot(Bas, att_src/att_dst)
    if (isP && tid < 128) {
      int isdst = tid >> 6, lane = tid & 63;
      const float* att = (isdst ? adst : asrc) + h * 256;
      float acc = 0.f;
      #pragma unroll
      for (int i = 0; i < 4; ++i)
        acc += s_bas[lane * 4 + i] * att[lane * 4 + i];
      for (int off = 32; off; off >>= 1) acc += __shfl_xor(acc, off);
      if (lane == 0) ws[WS_SC + isdst * 15 + t] = acc;
    }
  } else {
    // --- HC: 128 outputs, 2 k-halves
    __shared__ float hred[2][128];
    int c = tid & 127, half = tid >> 7;
    const float* w1a = w1 + (half * 128) * 128 + c;
    const float* w1b = w1 + (256 + half * 128) * 128 + c;
    const float* gbp = gb + half * 128;
    float acc = 0.f;
    #pragma unroll 32
    for (int i = 0; i < 128; ++i) acc += gbp[i] * (w1a[i * 128] + w1b[i * 128]);
    hred[half][c] = acc;
    __syncthreads();
    if (tid < 128) ws[WS_HC + tid] = b1[tid] + hred[0][tid] + hred[1][tid];
  }
}

// ---------------- K1: one block per graph ----------------
__global__ __launch_bounds__(256) void k1(const float* __restrict__ x,
                                          const int* __restrict__ prev,
                                          const int* __restrict__ cni,
                                          const int* __restrict__ gid,
                                          const float* __restrict__ w2,
                                          const float* __restrict__ b2,
                                          const float* __restrict__ ws,
                                          float* __restrict__ out) {
  __shared__ float s_x[C][2], s_xp[C][2];
  __shared__ float s_as[HEADS][C], s_ad[HEADS][C];
  __shared__ float s_co[C][17];
  __shared__ float s_h1[C][129];
  __shared__ float s_logits[64];
  __shared__ float s_w2[132];

  int g = blockIdx.x;
  int t = threadIdx.x;
  int base = g * C;

  if (t < C) {
    int p = prev[base + t];
    s_x[t][0] = x[(base + t) * 2 + 0];
    s_x[t][1] = x[(base + t) * 2 + 1];
    s_xp[t][0] = x[p * 2 + 0];
    s_xp[t][1] = x[p * 2 + 1];
  }
  if (t < 130) s_w2[t] = w2[t];
  __syncthreads();

  if (t < HEADS * C) {
    int h = t / C, j = t % C;
    float xp0 = s_xp[j][0], xp1 = s_xp[j][1], x0 = s_x[j][0], x1 = s_x[j][1];
    const float* sc = ws + WS_SC + h * 5;
    const float* dc = ws + WS_SC + 15 + h * 5;
    s_as[h][j] = xp0 * sc[0] + xp1 * sc[1] + x0 * sc[2] + x1 * sc[3] + sc[4];
    s_ad[h][j] = xp0 * dc[0] + xp1 * dc[1] + x0 * dc[2] + x1 * dc[3] + dc[4];
  }
  __syncthreads();

  if (t < HEADS * C) {
    int h = t / C, j = t % C;
    float adj = s_ad[h][j];
    float m = -1e30f;
    for (int i = 0; i < C; ++i) {
      float e = s_as[h][i] + adj;
      e = fmaxf(e, 0.2f * e);
      m = fmaxf(m, e);
    }
    float sum = 0.f, c0 = 0.f, c1 = 0.f, c2 = 0.f, c3 = 0.f;
    for (int i = 0; i < C; ++i) {
      float e = s_as[h][i] + adj;
      e = fmaxf(e, 0.2f * e);
      float ex = __expf(e - m);
      sum += ex;
      c0 += ex * s_xp[i][0];
      c1 += ex * s_xp[i][1];
      c2 += ex * s_x[i][0];
      c3 += ex * s_x[i][1];
    }
    float inv = 1.0f / (3.0f * sum);
    s_co[j][h * 5 + 0] = c0 * inv;
    s_co[j][h * 5 + 1] = c1 * inv;
    s_co[j][h * 5 + 2] = c2 * inv;
    s_co[j][h * 5 + 3] = c3 * inv;
    s_co[j][h * 5 + 4] = sum * inv;
  }
  __syncthreads();

  // h1[j][c] = relu(hc[c] + co[center].Qcol + co[j].Pcol)
  {
    int c0l = cni[g] - base;
    int c = t & 127;
    int jh = t >> 7;
    float Pcol[15], Qcol[15];
    #pragma unroll
    for (int r = 0; r < 15; ++r) {
      Pcol[r] = ws[WS_P + r * 128 + c];
      Qcol[r] = ws[WS_Q + r * 128 + c];
    }
    float cen = ws[WS_HC + c];
    #pragma unroll
    for (int r = 0; r < 15; ++r) cen += s_co[c0l][r] * Qcol[r];
    for (int mm = 0; mm < 25; ++mm) {
      int j = jh + 2 * mm;
      float acc = cen;
      #pragma unroll
      for (int r = 0; r < 15; ++r) acc += s_co[j][r] * Pcol[r];
      s_h1[j][c] = fmaxf(acc, 0.f);
    }
  }
  __syncthreads();

  // logits: 4 lanes per city
  if (t < 200) {
    int j = t >> 2, kk = t & 3;
    float acc = 0.f;
    #pragma unroll
    for (int k = 0; k < 32; ++k) acc += s_h1[j][kk * 32 + k] * s_w2[2 + kk * 32 + k];
    acc += __shfl_xor(acc, 1);
    acc += __shfl_xor(acc, 2);
    if (kk == 0)
      s_logits[j] = acc + b2[0] + s_x[j][0] * s_w2[0] + s_x[j][1] * s_w2[1];
  }
  __syncthreads();

  if (t < 64) {
    float v = (t < C) ? s_logits[t] : -1e30f;
    float mv = v; int mi = t;
    for (int off = 32; off > 0; off >>= 1) {
      float ov = __shfl_xor(mv, off);
      int oi = __shfl_xor(mi, off);
      if (ov > mv || (ov == mv && oi < mi)) { mv = ov; mi = oi; }
    }
    float ex = (t < C) ? __expf(v - mv) : 0.f;
    for (int off = 32; off > 0; off >>= 1) ex += __shfl_xor(ex, off);
    if (t == 0) {
      out[g] = (float)(mi + gid[g]);
      out[G + g] = -logf(ex);
    }
  }
}

extern "C" void kernel_launch(void* const* d_in, const int* in_sizes, int n_in,
                              void* d_out, int out_size, void* d_ws, size_t ws_size,
                              hipStream_t stream) {
  const float* x    = (const float*)d_in[0];
  const int*   prev = (const int*)d_in[2];
  const int*   cni  = (const int*)d_in[3];
  const int*   gid  = (const int*)d_in[4];
  const float* w0   = (const float*)d_in[6];
  const float* b0   = (const float*)d_in[7];
  const float* gw   = (const float*)d_in[8];
  const float* asrc = (const float*)d_in[9];
  const float* adst = (const float*)d_in[10];
  const float* gb   = (const float*)d_in[11];
  const float* w1   = (const float*)d_in[12];
  const float* b1   = (const float*)d_in[13];
  const float* w2   = (const float*)d_in[14];
  const float* b2   = (const float*)d_in[15];
  float* ws  = (float*)d_ws;
  float* out = (float*)d_out;

  kpre<<<31, 256, 0, stream>>>(w0, b0, gw, asrc, adst, w1, b1, gb, ws);
  k1<<<G, 256, 0, stream>>>(x, prev, cni, gid, w2, b2, ws, out);
}